// Round 7
// baseline (506.401 us; speedup 1.0000x reference)
//
#include <hip/hip_runtime.h>
#include <hip/hip_bf16.h>

#define F 64          // DIN == DOUT == 64
#define BK 128        // dst nodes per coarse bucket
#define NB 256        // build kernel grid: 1 block per CU -> co-resident

typedef __attribute__((ext_vector_type(8))) short bf16x8;
typedef __attribute__((ext_vector_type(4))) float f32x4;

static __device__ inline short f2bf_bits(float f) {
    union { __hip_bfloat16 b; short s; } cv;
    cv.b = __float2bfloat16(f);
    return cv.s;
}

// ---------------- h = x @ W via MFMA 16x16x32 bf16 ----------------
__global__ void gemm_kernel(const float* __restrict__ x, const float* __restrict__ W,
                            __hip_bfloat16* __restrict__ h, int n) {
    __shared__ short Wb[F * F];  // bf16 bits, [k][n] n-fastest
    int tid = threadIdx.x;
    for (int i = tid; i < F * F; i += 256) Wb[i] = f2bf_bits(W[i]);
    __syncthreads();
    int lane = tid & 63;
    int wv = tid >> 6;       // 0..3
    int quad = lane >> 4;    // 0..3
    int l16 = lane & 15;

    bf16x8 bfr[2][4];
#pragma unroll
    for (int ks = 0; ks < 2; ++ks)
#pragma unroll
        for (int nb = 0; nb < 4; ++nb) {
            bf16x8 f;
#pragma unroll
            for (int j = 0; j < 8; ++j) {
                int k = ks * 32 + quad * 8 + j;
                f[j] = Wb[k * F + nb * 16 + l16];
            }
            bfr[ks][nb] = f;
        }

    int blockbase = blockIdx.x * 256;
#pragma unroll
    for (int mt = 0; mt < 4; ++mt) {
        int trow = blockbase + (wv * 4 + mt) * 16;
        int ar = trow + l16;
        bf16x8 af0, af1;
        if (ar < n) {
            const float* xr = x + (size_t)ar * F + quad * 8;
            float4 v0 = ((const float4*)xr)[0];
            float4 v1 = ((const float4*)xr)[1];
            float4 v2 = ((const float4*)(xr + 32))[0];
            float4 v3 = ((const float4*)(xr + 32))[1];
            af0[0] = f2bf_bits(v0.x); af0[1] = f2bf_bits(v0.y);
            af0[2] = f2bf_bits(v0.z); af0[3] = f2bf_bits(v0.w);
            af0[4] = f2bf_bits(v1.x); af0[5] = f2bf_bits(v1.y);
            af0[6] = f2bf_bits(v1.z); af0[7] = f2bf_bits(v1.w);
            af1[0] = f2bf_bits(v2.x); af1[1] = f2bf_bits(v2.y);
            af1[2] = f2bf_bits(v2.z); af1[3] = f2bf_bits(v2.w);
            af1[4] = f2bf_bits(v3.x); af1[5] = f2bf_bits(v3.y);
            af1[6] = f2bf_bits(v3.z); af1[7] = f2bf_bits(v3.w);
        } else {
            af0 = (bf16x8)0; af1 = (bf16x8)0;
        }
        f32x4 acc[4];
#pragma unroll
        for (int nb = 0; nb < 4; ++nb) {
            acc[nb] = (f32x4)0.f;
            acc[nb] = __builtin_amdgcn_mfma_f32_16x16x32_bf16(af0, bfr[0][nb], acc[nb], 0, 0, 0);
            acc[nb] = __builtin_amdgcn_mfma_f32_16x16x32_bf16(af1, bfr[1][nb], acc[nb], 0, 0, 0);
        }
#pragma unroll
        for (int nb = 0; nb < 4; ++nb) {
#pragma unroll
            for (int r = 0; r < 4; ++r) {
                int grow = trow + quad * 4 + r;
                if (grow < n) {
                    h[(size_t)grow * F + nb * 16 + l16] = __float2bfloat16(acc[nb][r]);
                }
            }
        }
    }
}

// ---------------- grid barrier (manual, device scope) ----------------
// Grid is NB=256 blocks (1 per CU) -> all co-resident; per-phase counters,
// zeroed before each launch, so graph replays are safe.
static __device__ __forceinline__ void grid_barrier(unsigned* bar, int phase) {
    __syncthreads();
    if (threadIdx.x == 0) {
        __threadfence();  // release: make prior writes device-visible
        __hip_atomic_fetch_add(&bar[phase], 1u, __ATOMIC_ACQ_REL, __HIP_MEMORY_SCOPE_AGENT);
        while (__hip_atomic_load(&bar[phase], __ATOMIC_ACQUIRE, __HIP_MEMORY_SCOPE_AGENT)
               < (unsigned)NB) {
            __builtin_amdgcn_s_sleep(1);
        }
    }
    __syncthreads();
    __threadfence();  // acquire: invalidate caches so we see others' writes
}

// ---------------- build: count -> scan -> place -> per-bucket sort ----------------
// Deterministic two-level counting sort, zero global atomics.
__global__ void __launch_bounds__(256, 1)
build_kernel(const int* __restrict__ row, const int* __restrict__ col,
             unsigned* __restrict__ bar, int* __restrict__ blockhist /* -> base */,
             int* __restrict__ btot, int* __restrict__ bstart,
             unsigned* __restrict__ bin, int* __restrict__ csr,
             int4* __restrict__ rng4, __hip_bfloat16* __restrict__ h,
             int n, int e, int K, int chunk) {
    __shared__ int lh[1024];    // P1 histogram / P4 cursors
    __shared__ int ssum[256];   // P3 scan
    __shared__ int lcnt[BK];
    __shared__ int lcur[BK];
    __shared__ int sc[BK];
    __shared__ float sdinv[BK];

    int tid = threadIdx.x;
    int b = blockIdx.x;
    int s = b * chunk;
    int lim = min(s + chunk, e);

    // ---- P1: per-block histogram over K coarse buckets ----
    for (int i = tid; i < K; i += 256) lh[i] = 0;
    __syncthreads();
    for (int i = s + tid; i < lim; i += 256) atomicAdd(&lh[col[i] >> 7], 1);
    __syncthreads();
    for (int k = tid; k < K; k += 256) blockhist[b * K + k] = lh[k];

    grid_barrier(bar, 0);

    // ---- P2: per-bucket exclusive prefix over blocks (in-place) + totals ----
    int g = b * 256 + tid;
    if (g < K) {
        int acc = 0;
        for (int blk = 0; blk < NB; ++blk) {
            int v = blockhist[blk * K + g];
            blockhist[blk * K + g] = acc;  // exclusive prefix -> base
            acc += v;
        }
        btot[g] = acc;
    }

    grid_barrier(bar, 1);

    // ---- P3: block 0 scans bucket totals -> bstart (exclusive) ----
    if (b == 0) {
        int seg = (K + 255) / 256;  // <= 8
        int loc[8];
        int base0 = tid * seg;
        int a = 0;
        for (int j = 0; j < seg; ++j) {
            int idx = base0 + j;
            int v = (idx < K) ? btot[idx] : 0;
            loc[j] = a;
            a += v;
        }
        ssum[tid] = a;
        __syncthreads();
        for (int off = 1; off < 256; off <<= 1) {
            int t = (tid >= off) ? ssum[tid - off] : 0;
            __syncthreads();
            ssum[tid] += t;
            __syncthreads();
        }
        int segbase = (tid == 0) ? 0 : ssum[tid - 1];
        for (int j = 0; j < seg; ++j) {
            int idx = base0 + j;
            if (idx < K) bstart[idx] = segbase + loc[j];
        }
    }

    grid_barrier(bar, 2);

    // ---- P4: place packed entries via LDS cursors (exact offsets, no global atomics) ----
    for (int k = tid; k < K; k += 256) lh[k] = bstart[k] + blockhist[b * K + k];
    __syncthreads();
    for (int i = s + tid; i < lim; i += 256) {
        int d = col[i];
        int bkt = d >> 7;
        int pos = atomicAdd(&lh[bkt], 1);
        bin[pos] = ((unsigned)row[i] << 7) | ((unsigned)d & 127u);
    }

    grid_barrier(bar, 3);

    // ---- P5: per-bucket exact sort + rng4 + h *= dinv ----
    for (int k = b; k < K; k += NB) {
        __syncthreads();
        int bs = bstart[k];
        int be = bs + btot[k];
        int base = k << 7;
        if (tid < BK) lcnt[tid] = 0;
        __syncthreads();
        for (int p = bs + tid; p < be; p += 256) atomicAdd(&lcnt[bin[p] & 127u], 1);
        __syncthreads();
        if (tid < BK) sc[tid] = lcnt[tid];
        __syncthreads();
        for (int off = 1; off < BK; off <<= 1) {
            int t = (tid < BK && tid >= off) ? sc[tid - off] : 0;
            __syncthreads();
            if (tid < BK) sc[tid] += t;
            __syncthreads();
        }
        if (tid < BK) {
            int cnt = lcnt[tid];
            int lstart = sc[tid] - cnt;  // exclusive
            lcur[tid] = lstart;
            int node = base + tid;
            if (node < n) {
                int gs = bs + lstart;
                float di = rsqrtf((float)(cnt + 1));
                rng4[node] = make_int4(gs, gs + cnt, __float_as_int(di), 0);
                sdinv[tid] = di;
            }
        }
        __syncthreads();
        for (int p = bs + tid; p < be; p += 256) {
            unsigned u = bin[p];
            int ld = (int)(u & 127u);
            int pos = bs + atomicAdd(&lcur[ld], 1);
            csr[pos] = (int)(u >> 7);
        }
        int limh = BK * F;
        for (int idx = tid; idx < limh; idx += 256) {
            int node = base + (idx >> 6);
            if (node < n) {
                float di = sdinv[idx >> 6];
                size_t off = (size_t)node * F + (idx & 63);
                h[off] = __float2bfloat16(di * __bfloat162float(h[off]));
            }
        }
    }
}

// ---------------- gather: 2 nodes per wave, bf16x2 lanes, unroll 8 ----------------
__global__ void gather_kernel(const __hip_bfloat16* __restrict__ h,
                              const int* __restrict__ csr,
                              const int4* __restrict__ rng4,
                              const float* __restrict__ b,
                              float* __restrict__ out, int n) {
    int gid = blockIdx.x * 256 + threadIdx.x;
    int i = gid >> 5;  // node; 2 nodes per wave
    if (i >= n) return;
    int cl = gid & 31; // dword index within row (2 channels)
    const __hip_bfloat162* h2 = (const __hip_bfloat162*)h;  // [n][32]
    int4 r4 = rng4[i];
    int p = r4.x, pend = r4.y;
    float di = __int_as_float(r4.z);
    float2 acc = __bfloat1622float2(h2[(size_t)i * 32 + cl]);  // self-loop
    for (; p + 8 <= pend; p += 8) {
        int s0 = csr[p];     int s1 = csr[p + 1];
        int s2 = csr[p + 2]; int s3 = csr[p + 3];
        int s4 = csr[p + 4]; int s5 = csr[p + 5];
        int s6 = csr[p + 6]; int s7 = csr[p + 7];
        float2 a0 = __bfloat1622float2(h2[(size_t)s0 * 32 + cl]);
        float2 a1 = __bfloat1622float2(h2[(size_t)s1 * 32 + cl]);
        float2 a2 = __bfloat1622float2(h2[(size_t)s2 * 32 + cl]);
        float2 a3 = __bfloat1622float2(h2[(size_t)s3 * 32 + cl]);
        float2 a4 = __bfloat1622float2(h2[(size_t)s4 * 32 + cl]);
        float2 a5 = __bfloat1622float2(h2[(size_t)s5 * 32 + cl]);
        float2 a6 = __bfloat1622float2(h2[(size_t)s6 * 32 + cl]);
        float2 a7 = __bfloat1622float2(h2[(size_t)s7 * 32 + cl]);
        acc.x += ((a0.x + a1.x) + (a2.x + a3.x)) + ((a4.x + a5.x) + (a6.x + a7.x));
        acc.y += ((a0.y + a1.y) + (a2.y + a3.y)) + ((a4.y + a5.y) + (a6.y + a7.y));
    }
    for (; p + 4 <= pend; p += 4) {
        int s0 = csr[p];     int s1 = csr[p + 1];
        int s2 = csr[p + 2]; int s3 = csr[p + 3];
        float2 a0 = __bfloat1622float2(h2[(size_t)s0 * 32 + cl]);
        float2 a1 = __bfloat1622float2(h2[(size_t)s1 * 32 + cl]);
        float2 a2 = __bfloat1622float2(h2[(size_t)s2 * 32 + cl]);
        float2 a3 = __bfloat1622float2(h2[(size_t)s3 * 32 + cl]);
        acc.x += (a0.x + a1.x) + (a2.x + a3.x);
        acc.y += (a0.y + a1.y) + (a2.y + a3.y);
    }
    for (; p < pend; ++p) {
        float2 a = __bfloat1622float2(h2[(size_t)csr[p] * 32 + cl]);
        acc.x += a.x;
        acc.y += a.y;
    }
    float2 bb = ((const float2*)b)[cl];
    float vx = di * acc.x + bb.x;
    float vy = di * acc.y + bb.y;
    float2 res = make_float2(vx > 0.f ? vx : 0.f, vy > 0.f ? vy : 0.f);
    ((float2*)out)[(size_t)i * 32 + cl] = res;
}

extern "C" void kernel_launch(void* const* d_in, const int* in_sizes, int n_in,
                              void* d_out, int out_size, void* d_ws, size_t ws_size,
                              hipStream_t stream) {
    const float* x = (const float*)d_in[0];
    const int* ei  = (const int*)d_in[1];
    const float* W = (const float*)d_in[2];
    const float* b = (const float*)d_in[3];
    float* out = (float*)d_out;

    int n = in_sizes[0] / F;   // 100000
    int e = in_sizes[1] / 2;   // 1000000
    const int* row = ei;       // source
    const int* col = ei + e;   // target
    int K = (n + BK - 1) / BK; // 782

    // workspace layout (~24 MB)
    __hip_bfloat16* h = (__hip_bfloat16*)d_ws;                    // n*F bf16  12.8 MB
    unsigned* bin  = (unsigned*)((char*)d_ws + (size_t)n * F * 2); // e          4 MB
    int* csr       = (int*)(bin + e);                             // e          4 MB
    int4* rng4     = (int4*)(csr + e);                            // n          1.6 MB
    int* blockhist = (int*)(rng4 + n);                            // NB*K       0.8 MB
    int* btot      = blockhist + NB * K;                          // K
    int* bstart    = btot + K;                                    // K
    unsigned* bar  = (unsigned*)(bstart + K);                     // 8

    int chunk = (e + NB - 1) / NB;

    // 1. h = x @ W (bf16) via MFMA
    gemm_kernel<<<(n + 255) / 256, 256, 0, stream>>>(x, W, h, n);

    // 2. zero barrier counters (workspace is poisoned before every launch)
    hipMemsetAsync(bar, 0, 8 * sizeof(unsigned), stream);

    // 3. fused CSR build (count/scan/place/bucket-sort + h*=dinv), 1 block/CU
    build_kernel<<<NB, 256, 0, stream>>>(row, col, bar, blockhist, btot, bstart,
                                         bin, csr, rng4, h, n, e, K, chunk);

    // 4. gather + self-loop + bias + relu
    gather_kernel<<<((size_t)n * 32 + 255) / 256, 256, 0, stream>>>(
        h, csr, rng4, b, out, n);
}